// Round 3
// baseline (413.051 us; speedup 1.0000x reference)
//
#include <hip/hip_runtime.h>
#include <hip/hip_bf16.h>

#define RS 0.9999950000374998f  // 1/sqrt(1+1e-5)

__device__ __forceinline__ float eluf(float x) {
    return x > 0.0f ? x : expf(x) - 1.0f;
}

// ---------------------------------------------------------------------------
// Generic tiled f32 GEMM: out[r, c] = post(sum_k A[r,k] * W[k,c] + bias[c])
// post: ACT -> elu; BN -> *gamma/sqrt(1+eps) + beta
// rows multiple of 64, Ncols multiple of 64, Kdim multiple of 16.
// block 256, grid (rows/64, Ncols/64)
// ---------------------------------------------------------------------------
template <int ACT, int BN>
__global__ __launch_bounds__(256) void gemm_bias_act(
    const float* __restrict__ A, const float* __restrict__ W,
    const float* __restrict__ bias, const float* __restrict__ gamma,
    const float* __restrict__ beta, float* __restrict__ out,
    int Kdim, int Ncols) {
    __shared__ float As[16][64];
    __shared__ float Bs[16][64];
    const int tid = threadIdx.x;
    const int tx = tid & 15, ty = tid >> 4;
    const long row0 = (long)blockIdx.x * 64;
    const int col0 = blockIdx.y * 64;
    const int rA = tid >> 2, kqA = (tid & 3) << 2;
    const int kkB = tid >> 4, cqB = (tid & 15) << 2;
    float acc[4][4] = {};
    for (int k0 = 0; k0 < Kdim; k0 += 16) {
        const float4 av = *reinterpret_cast<const float4*>(
            A + (row0 + rA) * (long)Kdim + (k0 + kqA));
        const float4 bv = *reinterpret_cast<const float4*>(
            W + (long)(k0 + kkB) * Ncols + (col0 + cqB));
        As[kqA + 0][rA] = av.x;
        As[kqA + 1][rA] = av.y;
        As[kqA + 2][rA] = av.z;
        As[kqA + 3][rA] = av.w;
        *reinterpret_cast<float4*>(&Bs[kkB][cqB]) = bv;
        __syncthreads();
#pragma unroll
        for (int kk = 0; kk < 16; ++kk) {
            float a[4], b[4];
#pragma unroll
            for (int i = 0; i < 4; ++i) a[i] = As[kk][ty * 4 + i];
#pragma unroll
            for (int j = 0; j < 4; ++j) b[j] = Bs[kk][tx * 4 + j];
#pragma unroll
            for (int i = 0; i < 4; ++i)
#pragma unroll
                for (int j = 0; j < 4; ++j) acc[i][j] = fmaf(a[i], b[j], acc[i][j]);
        }
        __syncthreads();
    }
#pragma unroll
    for (int j = 0; j < 4; ++j) {
        const int col = col0 + tx * 4 + j;
        const float bb = bias[col];
        const float gs = BN ? gamma[col] * RS : 0.0f;
        const float bt = BN ? beta[col] : 0.0f;
#pragma unroll
        for (int i = 0; i < 4; ++i) {
            const long row = row0 + ty * 4 + i;
            float v = acc[i][j] + bb;
            if (ACT) v = eluf(v);
            if (BN) v = v * gs + bt;
            out[row * Ncols + col] = v;
        }
    }
}

// ---------------------------------------------------------------------------
// Setup: per point, gather neighbor coords, compute pts_local (store) and
// Xc[gp, o] = elu(sum_{d,k} pts_local[k,d] * xt_cW[o,d,k] + cb[o])  (store)
// 16 points per block, 256 threads. grid = 32768/16 = 2048.
// ---------------------------------------------------------------------------
__global__ __launch_bounds__(256) void setup_kernel(
    const float* __restrict__ rep_pts, const float* __restrict__ pts,
    const int* __restrict__ pts_idx, const float* __restrict__ xt_cW,
    const float* __restrict__ xt_cb, float* __restrict__ pts_local,
    float* __restrict__ Xc) {
    __shared__ float cwT[48][256];  // cwT[d*16+k][o] = xt_cW[o,d,k]
    __shared__ float pl2[16][48];   // pl2[pt][d*16+k]
    __shared__ float cb_s[256];
    const int tid = threadIdx.x;
    const long gp0 = (long)blockIdx.x * 16;
#pragma unroll
    for (int i = 0; i < 48; ++i) cwT[i][tid] = xt_cW[tid * 48 + i];
    cb_s[tid] = xt_cb[tid];
    {
        const int pt = tid >> 4, k = tid & 15;
        const long gp = gp0 + pt;
        const int n = (int)(gp >> 11);
        const int idx = pts_idx[gp * 32 + 2 * k];
        const float* ps = pts + ((long)n * 8192 + idx) * 3;
        const float* rs = rep_pts + gp * 3;
        float* plo = pts_local + gp * 48 + k * 3;
#pragma unroll
        for (int d = 0; d < 3; ++d) {
            const float v = ps[d] - rs[d];
            pl2[pt][d * 16 + k] = v;
            plo[d] = v;
        }
    }
    __syncthreads();
    const int o = tid;
    for (int pt = 0; pt < 16; ++pt) {
        float acc = cb_s[o];
#pragma unroll
        for (int i = 0; i < 48; ++i) acc = fmaf(pl2[pt][i], cwT[i][o], acc);
        Xc[(gp0 + pt) * 256 + o] = eluf(acc);
    }
}

// ---------------------------------------------------------------------------
// Final per-point stage, wave-per-point column-owner layout.
// Block = 256 threads = 4 waves = 4 points. grid = 32768/4 = 8192.
// Lane l owns fcat columns c0 = l (all lanes) and c1 = 64+l (lanes < 32).
//   fcat col 0..31  = lifted  (owned as c0 by lanes 0..31)
//   fcat col 32..63 = fts col 0..31  (owned as c0 by lanes 32..63)
//   fcat col 64..95 = fts col 32..63 (owned as c1 by lanes 0..31)
// fts_X accumulators live in registers; dw is fully lane-local.
// ---------------------------------------------------------------------------
__global__ __launch_bounds__(256) void final_stage_kernel(
    const float* __restrict__ X2,         // [32768][256]
    const float* __restrict__ pts_local,  // [32768][48] (k*3+d)
    const int* __restrict__ pts_idx,
    const float* __restrict__ fts_l,  // [16*8192][64]
    const float* __restrict__ d1_W, const float* __restrict__ d1_b,
    const float* __restrict__ d1_g, const float* __restrict__ d1_bt,
    const float* __restrict__ d2_W, const float* __restrict__ d2_b,
    const float* __restrict__ d2_g, const float* __restrict__ d2_bt,
    const float* __restrict__ dw_W, const float* __restrict__ dw_b,
    float* __restrict__ dw_out)  // [32768][192]
{
    __shared__ float X_s[4][256];       // X row per point (broadcast reads)
    __shared__ float l0_s[4][16][32];   // l0, then reused for lifted
    __shared__ float pl_s[4][48];
    __shared__ int idx_s[4][16];
    __shared__ float dwT[2][16][101];   // dwT[m][k][c] = dw_W[c][m][k], padded

    const int tid = threadIdx.x;
    const int w = tid >> 6;   // wave = point within block
    const int l = tid & 63;   // lane
    const long gp = (long)blockIdx.x * 4 + w;
    const int n = (int)(gp >> 11);
    const int c32 = l & 31, h = l >> 5;

    // ---- stage inputs ----
    *reinterpret_cast<float4*>(&X_s[w][l * 4]) =
        *reinterpret_cast<const float4*>(&X2[gp * 256 + l * 4]);
    if (l < 16) idx_s[w][l] = pts_idx[gp * 32 + 2 * l];
    if (l < 48) pl_s[w][l] = pts_local[gp * 48 + l];
    // dw_W has 96*2*16 = 3072 elements; 12 * 256 = 3072 (24 was OOB garbage!)
#pragma unroll
    for (int i = 0; i < 12; ++i) {
        const int e = i * 256 + tid;  // e = c*32 + m*16 + k
        const int c = e >> 5, r = e & 31;
        dwT[r >> 4][r & 15][c] = dw_W[e];
    }
    __syncthreads();

    // ---- gather fts column into regs: fg[j] = fts_l[idx[j]][colg] ----
    const int colg = (l < 32) ? (32 + l) : (l - 32);
    float fg[16];
    const float* fbase = fts_l + (long)n * 8192 * 64 + colg;
#pragma unroll
    for (int j = 0; j < 16; ++j) fg[j] = fbase[(long)idx_s[w][j] * 64];

    // ---- l0: lane (c32,h) computes rows h*8..h*8+7 of col c32 ----
    {
        const float w0 = d1_W[0 * 32 + c32], w1 = d1_W[1 * 32 + c32],
                    w2 = d1_W[2 * 32 + c32];
        const float b = d1_b[c32], gsc = d1_g[c32] * RS, bt = d1_bt[c32];
#pragma unroll
        for (int jl = 0; jl < 8; ++jl) {
            const int j = h * 8 + jl;
            float a = b;
            a = fmaf(pl_s[w][j * 3 + 0], w0, a);
            a = fmaf(pl_s[w][j * 3 + 1], w1, a);
            a = fmaf(pl_s[w][j * 3 + 2], w2, a);
            a = eluf(a);
            l0_s[w][j][c32] = a * gsc + bt;
        }
    }
    __syncthreads();

    // ---- lifted: lane (c32,h) computes rows h*8..h*8+7 of col c32 ----
    float lf[8];
    {
        float d2w[32];
#pragma unroll
        for (int q = 0; q < 32; ++q) d2w[q] = d2_W[q * 32 + c32];
        const float b = d2_b[c32];
#pragma unroll
        for (int jl = 0; jl < 8; ++jl) lf[jl] = b;
#pragma unroll
        for (int q4 = 0; q4 < 8; ++q4) {
#pragma unroll
            for (int jl = 0; jl < 8; ++jl) {
                const float4 lv = *reinterpret_cast<const float4*>(
                    &l0_s[w][h * 8 + jl][q4 * 4]);
                lf[jl] = fmaf(lv.x, d2w[q4 * 4 + 0], lf[jl]);
                lf[jl] = fmaf(lv.y, d2w[q4 * 4 + 1], lf[jl]);
                lf[jl] = fmaf(lv.z, d2w[q4 * 4 + 2], lf[jl]);
                lf[jl] = fmaf(lv.w, d2w[q4 * 4 + 3], lf[jl]);
            }
        }
        const float gsc = d2_g[c32] * RS, bt = d2_bt[c32];
#pragma unroll
        for (int jl = 0; jl < 8; ++jl) lf[jl] = eluf(lf[jl]) * gsc + bt;
    }
    __syncthreads();  // all reads of l0 done; now overwrite with lifted
#pragma unroll
    for (int jl = 0; jl < 8; ++jl) l0_s[w][h * 8 + jl][c32] = lf[jl];
    __syncthreads();

    // ---- fA[j]: lanes<32 -> lifted col l; lanes>=32 -> fg (fts col l-32) ----
    float fA[16];
#pragma unroll
    for (int j = 0; j < 16; ++j) {
        const float flv = l0_s[w][j][c32];
        fA[j] = (l < 32) ? flv : fg[j];
    }

    // ---- fts_X: accA[i] = sum_j X[i][j]*fA[j]; accB[i] = sum_j X[i][j]*fg[j]
    float accA[16], accB[16];
#pragma unroll
    for (int i = 0; i < 16; ++i) {
        accA[i] = 0.0f;
        accB[i] = 0.0f;
    }
#pragma unroll
    for (int i = 0; i < 16; ++i) {
#pragma unroll
        for (int j4 = 0; j4 < 4; ++j4) {
            const float4 xv =
                *reinterpret_cast<const float4*>(&X_s[w][i * 16 + j4 * 4]);
            accA[i] = fmaf(xv.x, fA[j4 * 4 + 0], accA[i]);
            accA[i] = fmaf(xv.y, fA[j4 * 4 + 1], accA[i]);
            accA[i] = fmaf(xv.z, fA[j4 * 4 + 2], accA[i]);
            accA[i] = fmaf(xv.w, fA[j4 * 4 + 3], accA[i]);
            accB[i] = fmaf(xv.x, fg[j4 * 4 + 0], accB[i]);
            accB[i] = fmaf(xv.y, fg[j4 * 4 + 1], accB[i]);
            accB[i] = fmaf(xv.z, fg[j4 * 4 + 2], accB[i]);
            accB[i] = fmaf(xv.w, fg[j4 * 4 + 3], accB[i]);
        }
    }

    // ---- dw: lane-local. col c0 = l (accA); col c1 = 64+l lanes<32 (accB) --
    {
        float o0 = dw_b[2 * l + 0], o1 = dw_b[2 * l + 1];
#pragma unroll
        for (int k = 0; k < 16; ++k) {
            o0 = fmaf(accA[k], dwT[0][k][l], o0);
            o1 = fmaf(accA[k], dwT[1][k][l], o1);
        }
        *reinterpret_cast<float2*>(&dw_out[gp * 192 + 2 * l]) =
            make_float2(o0, o1);
        if (l < 32) {
            const int c1 = 64 + l;
            float p0 = dw_b[2 * c1 + 0], p1 = dw_b[2 * c1 + 1];
#pragma unroll
            for (int k = 0; k < 16; ++k) {
                p0 = fmaf(accB[k], dwT[0][k][c1], p0);
                p1 = fmaf(accB[k], dwT[1][k][c1], p1);
            }
            *reinterpret_cast<float2*>(&dw_out[gp * 192 + 2 * c1]) =
                make_float2(p0, p1);
        }
    }
}

extern "C" void kernel_launch(void* const* d_in, const int* in_sizes, int n_in,
                              void* d_out, int out_size, void* d_ws,
                              size_t ws_size, hipStream_t stream) {
    const float* rep_pts = (const float*)d_in[0];
    const float* pts = (const float*)d_in[1];
    const float* fts = (const float*)d_in[2];
    const int* pts_idx = (const int*)d_in[3];
    const float* dense_W = (const float*)d_in[4];
    const float* dense_b = (const float*)d_in[5];
    const float* dense_g = (const float*)d_in[6];
    const float* dense_bt = (const float*)d_in[7];
    const float* d1_W = (const float*)d_in[8];
    const float* d1_b = (const float*)d_in[9];
    const float* d1_g = (const float*)d_in[10];
    const float* d1_bt = (const float*)d_in[11];
    const float* d2_W = (const float*)d_in[12];
    const float* d2_b = (const float*)d_in[13];
    const float* d2_g = (const float*)d_in[14];
    const float* d2_bt = (const float*)d_in[15];
    const float* xt_cW = (const float*)d_in[16];
    const float* xt_cb = (const float*)d_in[17];
    const float* xt_d1W = (const float*)d_in[18];
    const float* xt_d1b = (const float*)d_in[19];
    const float* xt_d2W = (const float*)d_in[20];
    const float* xt_d2b = (const float*)d_in[21];
    const float* dw_W = (const float*)d_in[22];
    const float* dw_b = (const float*)d_in[23];
    const float* pw_W = (const float*)d_in[24];
    const float* pw_b = (const float*)d_in[25];
    const float* sep_g = (const float*)d_in[26];
    const float* sep_bt = (const float*)d_in[27];

    float* ws = (float*)d_ws;
    float* fts_l = ws;               // 131072*64  = 8388608 f32
    float* bufA = ws + 8388608;      // Xc then X2 : 32768*256
    float* bufB = ws + 16777216;     // X1 then dw : 32768*256
    float* pl = ws + 25165824;       // 32768*48

    // 1) fts_l = bn(elu(fts @ dense_W + b))   (131072 x 64) @ (64 x 64)
    gemm_bias_act<1, 1><<<dim3(2048, 1), 256, 0, stream>>>(
        fts, dense_W, dense_b, dense_g, dense_bt, fts_l, 64, 64);

    // 2) pts_local + Xc
    setup_kernel<<<2048, 256, 0, stream>>>(rep_pts, pts, pts_idx, xt_cW, xt_cb,
                                           pl, bufA);

    // 3) X1 = elu(Xc @ xt_d1W + b)   (32768 x 256) @ (256 x 256)
    gemm_bias_act<1, 0><<<dim3(512, 4), 256, 0, stream>>>(
        bufA, xt_d1W, xt_d1b, nullptr, nullptr, bufB, 256, 256);

    // 4) X2 = X1 @ xt_d2W + b
    gemm_bias_act<0, 0><<<dim3(512, 4), 256, 0, stream>>>(
        bufB, xt_d2W, xt_d2b, nullptr, nullptr, bufA, 256, 256);

    // 5) lifted/gather/fts_X/dw -> bufB [32768][192]
    final_stage_kernel<<<8192, 256, 0, stream>>>(
        bufA, pl, pts_idx, fts_l, d1_W, d1_b, d1_g, d1_bt, d2_W, d2_b, d2_g,
        d2_bt, dw_W, dw_b, bufB);

    // 6) out = bn(elu(dw @ pw_W + pw_b))   (32768 x 192) @ (192 x 128)
    gemm_bias_act<1, 1><<<dim3(512, 2), 256, 0, stream>>>(
        bufB, pw_W, pw_b, sep_g, sep_bt, (float*)d_out, 192, 128);
}